// Round 9
// baseline (802.221 us; speedup 1.0000x reference)
//
#include <hip/hip_runtime.h>

// ---------------------------------------------------------------------------
// Problem constants (from the reference)
//   RS_IN = RS_OUT = [(16,0),(16,1),(16,2)], HIDDEN=100
//   N_IN = N_OUT = 144, N_PATH = 4864, B = 8192, SH l=0..4 (25 comps)
// ---------------------------------------------------------------------------
#define NB     8192
#define NPB    4          // points per block -> 2048 blocks, no tail
#define NPATH  4864
#define NHID   100
#define NROW   144
#define NYSH   25
#define NDPAD  312        // padded D floats per point (io-rows padded to x4)

typedef float v4f __attribute__((ext_vector_type(4)));   // NT-store compatible
typedef float v2f __attribute__((ext_vector_type(2)));   // v_pk_fma_f32 pairs

// Repacked bf16 W2: [i][t][24 shorts]; slots 0..18 = the 19 paths thread t
// consumes in the expansion, padded to 48 B for aligned vector loads.
__device__ __align__(16) unsigned short g_w2r[NHID * 256 * 24];
__device__ float g_cg[1225];

// ---------------------------------------------------------------------------
// Setup kernel: blocks 0..18 compute CG tables (fp64, exact port of the
// reference _cg_complex/_w3j/_Q/_real_cg); blocks 19.. repack W2 to bf16.
// ---------------------------------------------------------------------------
__device__ inline double dfact(int n) {
    const double F[13] = {1., 1., 2., 6., 24., 120., 720., 5040., 40320.,
                          362880., 3628800., 39916800., 479001600.};
    return F[n];
}

__device__ double cgc(int j1, int j2, int j3, int m1, int m2, int m3) {
    if (m1 + m2 != m3) return 0.0;
    double pref0 = sqrt((2 * j3 + 1) * dfact(j1 + j2 - j3) * dfact(j1 - j2 + j3) *
                        dfact(-j1 + j2 + j3) / dfact(j1 + j2 + j3 + 1));
    double pref = pref0 * sqrt(dfact(j3 + m3) * dfact(j3 - m3) * dfact(j1 - m1) *
                               dfact(j1 + m1) * dfact(j2 - m2) * dfact(j2 + m2));
    int klo = max(0, max(j2 - j3 - m1, j1 + m2 - j3));
    int khi = min(j1 + j2 - j3, min(j1 - m1, j2 + m2));
    double s = 0.0;
    for (int k = klo; k <= khi; k++) {
        double d = dfact(k) * dfact(j1 + j2 - j3 - k) * dfact(j1 - m1 - k) *
                   dfact(j2 + m2 - k) * dfact(j3 - j2 + m1 + k) * dfact(j3 - j1 - m2 + k);
        s += ((k & 1) ? -1.0 : 1.0) / d;
    }
    return pref * s;
}

__device__ double w3jf(int j1, int j2, int j3, int m1, int m2, int m3) {
    int e = j1 - j2 + m3;
    double sgn = (e & 1) ? -1.0 : 1.0;
    return sgn / sqrt((double)(2 * j3 + 1)) * cgc(j1, j2, j3, m1, m2, -m3);
}

// Nonzeros of row `a` of the complex->real change-of-basis Q(l).
__device__ int qrow(int l, int a, int* col, double* re, double* im) {
    const double s2 = 0.70710678118654752440;
    int m = a - l;
    if (m == 0) { col[0] = l; re[0] = 1.0; im[0] = 0.0; return 1; }
    if (m > 0) {
        col[0] = l + m; re[0] = (m & 1) ? -s2 : s2; im[0] = 0.0;
        col[1] = l - m; re[1] = s2;                 im[1] = 0.0;
        return 2;
    }
    int mm = -m;
    col[0] = l - mm; re[0] = 0.0; im[0] = s2;
    col[1] = l + mm; re[1] = 0.0; im[1] = (mm & 1) ? s2 : -s2;
    return 2;
}

__global__ void setup_kernel(const float* __restrict__ W2) {
    const int tid = threadIdx.x;
    const int bid = blockIdx.x;
    if (bid >= 19) {
        // Repack W2 to bf16 (round-to-nearest-even) in [i][t][j] layout.
        // Thread t's 19 expansion paths: j -> CBJ[j] + t*NLFJ[j] + KJ[j]
        int idx = (bid - 19) * 256 + tid;
        if (idx < NHID * 256 * 19) {
            const int CBJ[19]  = {0, 256, 512, 768, 1024, 1024, 1024, 1792, 1792, 1792,
                                  2560, 2816, 2816, 2816, 3584, 3584, 3584, 3584, 3584};
            const int NLFJ[19] = {1, 1, 1, 1, 3, 3, 3, 3, 3, 3, 1, 3, 3, 3, 5, 5, 5, 5, 5};
            const int KJ[19]   = {0, 0, 0, 0, 0, 1, 2, 0, 1, 2, 0, 0, 1, 2, 0, 1, 2, 3, 4};
            int j = idx % 19;
            int t = (idx / 19) & 255;
            int i = idx / (19 * 256);
            int p = CBJ[j] + t * NLFJ[j] + KJ[j];
            unsigned int u = __float_as_uint(W2[i * NPATH + p]);
            unsigned int rr = (u + 0x7fffu + ((u >> 16) & 1u)) >> 16;
            g_w2r[(i * 256 + t) * 24 + j] = (unsigned short)rr;
        }
        return;
    }
    // CG table metadata: (lo, li, lf) in reference dict-insertion order
    const int TLO[19]  = {0,0,0,1,1,1,1,1,1,1,2,2,2,2,2,2,2,2,2};
    const int TLI[19]  = {0,1,2,0,1,1,1,2,2,2,0,1,1,1,2,2,2,2,2};
    const int TLF[19]  = {0,1,2,1,0,1,2,1,2,3,2,1,2,3,0,1,2,3,4};
    const int TOFF[19] = {0,1,10,35,44,53,80,125,170,245,350,375,420,495,600,625,700,825,1000};
    const int lo = TLO[bid], li = TLI[bid], lf = TLF[bid];
    const int n1 = 2 * lo + 1, n2 = 2 * li + 1, n3 = 2 * lf + 1;
    const int E = n1 * n2 * n3;

    __shared__ double sre[256], sim[256];
    __shared__ double snorm;
    __shared__ int ssel;

    double vre = 0.0, vim = 0.0;
    if (tid < E) {
        int g = tid % n3; int ab = tid / n3; int b = ab % n2; int a = ab / n2;
        int ca[2], cb[2], cc[2];
        double ra[2], ia[2], rb[2], ib[2], rc[2], ic[2];
        int na = qrow(lo, a, ca, ra, ia);
        int nb = qrow(li, b, cb, rb, ib);
        int nc = qrow(lf, g, cc, rc, ic);
        for (int p = 0; p < na; p++)
            for (int q = 0; q < nb; q++) {
                double pr = ra[p] * rb[q] - ia[p] * ib[q];
                double pi = ra[p] * ib[q] + ia[p] * rb[q];
                for (int s = 0; s < nc; s++) {
                    double w = w3jf(lo, li, lf, ca[p] - lo, cb[q] - li, cc[s] - lf);
                    if (w == 0.0) continue;
                    vre += (pr * rc[s] - pi * ic[s]) * w;
                    vim += (pr * ic[s] + pi * rc[s]) * w;
                }
            }
    }
    sre[tid] = vre * vre;
    sim[tid] = vim * vim;
    __syncthreads();
    if (tid == 0) {
        double sr = 0.0, si = 0.0;
        for (int e = 0; e < E; e++) { sr += sre[e]; si += sim[e]; }
        sr = sqrt(sr); si = sqrt(si);
        ssel = (sr >= si) ? 0 : 1;
        snorm = ssel ? si : sr;
    }
    __syncthreads();
    if (tid < E) {
        double val = ssel ? vim : vre;
        g_cg[TOFF[bid] + tid] = (float)(val / snorm);
    }
}

// ---------------------------------------------------------------------------
// Expansion helpers. D lives in a per-pair padded LDS layout (PB = float base,
// PST = padded io-row stride in floats; 16-B aligned). Output pointer `o` may
// be an LDS slab row or a global row (both use row stride NROW).
// ---------------------------------------------------------------------------

// Pairs with NLF==1 and a single small chunk of NO*NI (<=5) floats at PB.
template <int NO, int NI, int CIDX, int PB, int NUM, int NA>
__device__ __forceinline__ void expand_small(const float (&A)[NA],
                                             const float* __restrict__ D,
                                             float* o, bool zero) {
    constexpr int T = NO * NI;
    const float PI4 = 12.566370614359172f;  // 4*pi
    const float n0 = sqrtf(NI * PI4 / (float)NUM);   // NI == 2*LI+1
    const float n1 = sqrtf(NI * PI4) * 0.25f;
    const float c0 = (zero ? n1 : n0) * A[CIDX];
    float rb[8];
    float4 t0 = *(const float4*)(D + PB);
    rb[0] = t0.x; rb[1] = t0.y; rb[2] = t0.z; rb[3] = t0.w;
    if constexpr (T > 4) rb[4] = D[PB + 4];
#pragma unroll
    for (int io = 0; io < NO; io++)
#pragma unroll
        for (int jo = 0; jo < NI; jo++)
            o[io * NROW + jo] = c0 * rb[io * NI + jo];
}

// Pairs with NLF>1: per-io float4 chunk reads of the padded row.
template <int NO, int NI, int NLF, int CIDX, int PB, int PST, int NUM, int NA>
__device__ __forceinline__ void expand_big(const float (&A)[NA],
                                           const float* __restrict__ D,
                                           float* o, bool zero) {
    constexpr int CH = (NI * NLF + 3) / 4;   // float4 chunks per io-row
    const float PI4 = 12.566370614359172f;
    const float n0 = sqrtf(NI * PI4 / (float)NUM);   // NI == 2*LI+1
    const float n1 = sqrtf(NI * PI4) * 0.25f;
    const float norm = zero ? n1 : n0;
    float c[NLF];
#pragma unroll
    for (int k = 0; k < NLF; k++) c[k] = norm * A[CIDX + k];
#pragma unroll
    for (int io = 0; io < NO; io++) {
        const float4* dp = (const float4*)(D + PB + io * PST);
        float rb[CH * 4];
#pragma unroll
        for (int q = 0; q < CH; q++) {
            float4 t = dp[q];
            rb[4 * q] = t.x; rb[4 * q + 1] = t.y; rb[4 * q + 2] = t.z; rb[4 * q + 3] = t.w;
        }
#pragma unroll
        for (int jo = 0; jo < NI; jo++) {
            float s = 0.0f;
#pragma unroll
            for (int k = 0; k < NLF; k++) s += rb[jo * NLF + k] * c[k];
            o[io * NROW + jo] = s;
        }
    }
}

// Coalesced non-temporal flush of a wave slab band: NROWS full 144-float rows.
template <int NROWS>
__device__ __forceinline__ void flush_band(const float* slabW, float* gdst,
                                           int lane) {
    constexpr int N4 = NROWS * NROW / 4;
    const v4f* s4 = (const v4f*)slabW;
    v4f* g4 = (v4f*)gdst;
#pragma unroll
    for (int c = 0; c < N4 / 64; c++) {
        v4f t = s4[c * 64 + lane];
        __builtin_nontemporal_store(t, &g4[c * 64 + lane]);
    }
    if constexpr (N4 % 64) {
        if (lane < (N4 % 64)) {
            v4f t = s4[(N4 / 64) * 64 + lane];
            __builtin_nontemporal_store(t, &g4[(N4 / 64) * 64 + lane]);
        }
    }
}

// ---------------------------------------------------------------------------
// Main fused kernel: 4 points per block, 256 threads, 2048 blocks (exact grid).
// Phases: SH+radius -> D(=CG*Y, padded) -> single-pass pk-FMA register GEMM ->
// expansion: LO=0/1 bands via per-wave LDS slabs + coalesced NT flush;
// LO=2 band via direct scattered stores (cheap: R7 showed slabbing everything
// bought only -19us; un-slabbing the 20-row band frees 45->27.6 KB).
// LDS ~33 KB + launch_bounds(256,4) -> 4 blocks/CU (was 3).
// ---------------------------------------------------------------------------
#define BF16LO(x) __uint_as_float((x) << 16)
#define BF16HI(x) __uint_as_float((x) & 0xffff0000u)

__global__ __launch_bounds__(256, 4) void tfn_kernel(const float* __restrict__ r,
                                                     const float* __restrict__ W1,
                                                     const float* __restrict__ b1,
                                                     float* __restrict__ out) {
    __shared__ float sY[NPB][NYSH];
    __shared__ float sD[NPB][NDPAD];       // 4 x 312 x 4B = 5 KB
    __shared__ float sSlab[4][12 * NROW];  // per-wave 12x144 band = 27.6 KB
    __shared__ float sRad[NPB];
    __shared__ int   sZero[NPB];

    const int tid = threadIdx.x;
    const int zbase = blockIdx.x * NPB;   // 2048*4 == 8192: no tail guards

    // ---- Phase 1: radius + spherical harmonics (threads 0..NPB-1) ----
    if (tid < NPB) {
        int z = zbase + tid;
        float* Y = sY[tid];
        float x = r[3 * z], y = r[3 * z + 1], zc = r[3 * z + 2];
        float rad = sqrtf(x * x + y * y + zc * zc);
        sRad[tid] = rad;
        sZero[tid] = (rad == 0.0f) ? 1 : 0;
        float inv = 1.0f / fmaxf(rad, 1e-12f);
        x *= inv; y *= inv; zc *= inv;
        float x2 = x * x, y2 = y * y, z2 = zc * zc;
        Y[0] = 0.28209479177387814f;
        Y[1] = 0.4886025119029199f * y;
        Y[2] = 0.4886025119029199f * zc;
        Y[3] = 0.4886025119029199f * x;
        Y[4] = 1.0925484305920792f * x * y;
        Y[5] = 1.0925484305920792f * y * zc;
        Y[6] = 0.31539156525252005f * (3.0f * z2 - 1.0f);
        Y[7] = 1.0925484305920792f * x * zc;
        Y[8] = 0.5462742152960396f * (x2 - y2);
        Y[9]  = 0.5900435899266435f * y * (3.0f * x2 - y2);
        Y[10] = 2.890611442640554f * x * y * zc;
        Y[11] = 0.4570457994644658f * y * (5.0f * z2 - 1.0f);
        Y[12] = 0.3731763325901154f * zc * (5.0f * z2 - 3.0f);
        Y[13] = 0.4570457994644658f * x * (5.0f * z2 - 1.0f);
        Y[14] = 1.445305721320277f * (x2 - y2) * zc;
        Y[15] = 0.5900435899266435f * x * (x2 - 3.0f * y2);
        Y[16] = 2.5033429417967046f * x * y * (x2 - y2);
        Y[17] = 1.7701307697799304f * y * (3.0f * x2 - y2) * zc;
        Y[18] = 0.9461746957575601f * x * y * (7.0f * z2 - 1.0f);
        Y[19] = 0.6690465435572892f * y * zc * (7.0f * z2 - 3.0f);
        Y[20] = 0.10578554691520431f * (35.0f * z2 * z2 - 30.0f * z2 + 3.0f);
        Y[21] = 0.6690465435572892f * x * zc * (7.0f * z2 - 3.0f);
        Y[22] = 0.47308734787878004f * (x2 - y2) * (7.0f * z2 - 1.0f);
        Y[23] = 1.7701307697799304f * x * (x2 - 3.0f * y2) * zc;
        Y[24] = 0.6258357354491761f * (x2 * x2 - 6.0f * x2 * y2 + y2 * y2);
    }
    __syncthreads();

    // ---- Phase 2: D[pair-padded] = sum_m CG[.,.,m] * Y[lf^2+m] ----
    {
        // unpadded decomposition tables (pair order 00,01,02,10,11,12,20,21,22)
        const int dbase[10] = {0, 1, 4, 9, 12, 39, 84, 89, 134, 259};
        const int pnlf[9]   = {1, 1, 1, 1, 3, 3, 1, 3, 5};
        const int plf0[9]   = {0, 1, 2, 1, 0, 1, 2, 1, 0};
        const int ptab0[9]  = {0, 1, 2, 3, 4, 7, 10, 11, 14};
        const int toff[19]  = {0,1,10,35,44,53,80,125,170,245,350,375,420,495,600,625,700,825,1000};
        // padded layout tables
        const int PBt[9]  = {0, 4, 8, 16, 20, 56, 104, 112, 172};
        const int PSTt[9] = {0, 0, 0, 0, 12, 16, 0, 12, 28};   // 0 = single chunk
        const int NIt[9]  = {1, 3, 5, 1, 3, 5, 1, 3, 5};
        for (int idx = tid; idx < NPB * 259; idx += 256) {
            int zz = idx / 259, e = idx - zz * 259;
            int pp = 8;
            while (e < dbase[pp]) pp--;
            int le = e - dbase[pp];
            int nlf = pnlf[pp];
            int rr = le / nlf, k = le - rr * nlf;
            int lf = plf0[pp] + k, nf = 2 * lf + 1;
            const float* cg = &g_cg[toff[ptab0[pp] + k] + rr * nf];
            const float* Yp = &sY[zz][lf * lf];
            float s = 0.0f;
            for (int m = 0; m < nf; m++) s += cg[m] * Yp[m];
            int pa;
            if (PSTt[pp] == 0) {
                pa = PBt[pp] + le;
            } else {
                int io = rr / NIt[pp];
                int jo = rr - io * NIt[pp];
                pa = PBt[pp] + io * PSTt[pp] + jo * nlf + k;
            }
            sD[zz][pa] = s;
        }
    }

    // ---- Phase 3: register GEMM with packed fp32 FMAs, no LDS in the loop.
    //      acc01[j] = {coeff(z0,path j), coeff(z1,path j)}, acc23 likewise.
    float rad0 = sRad[0], rad1 = sRad[1], rad2 = sRad[2], rad3 = sRad[3];
    v2f acc01[19], acc23[19];
#pragma unroll
    for (int j = 0; j < 19; j++) { acc01[j] = (v2f)0.0f; acc23[j] = (v2f)0.0f; }
    {
        const unsigned int* wp = (const unsigned int*)g_w2r + tid * 12;  // 48 B/thread
        for (int i = 0; i < NHID; i++) {
            uint4 a  = *(const uint4*)(wp);
            uint4 b  = *(const uint4*)(wp + 4);
            uint2 c2 = *(const uint2*)(wp + 8);
            wp += 256 * 12;
            float w1i = W1[i], b1i = b1[i];          // uniform -> s_load
            float h0 = fmaxf(rad0 * w1i + b1i, 0.0f);
            float h1 = fmaxf(rad1 * w1i + b1i, 0.0f);
            float h2 = fmaxf(rad2 * w1i + b1i, 0.0f);
            float h3 = fmaxf(rad3 * w1i + b1i, 0.0f);
            v2f h01 = {h0, h1}, h23 = {h2, h3};
            // 19 paths, direct component access (no arrays -> no scratch risk),
            // each path = 2x v_pk_fma_f32 (4 FMAs in 2 instrs).
#define PATHJ(J, EXPR) { float w_ = (EXPR); acc01[J] += h01 * w_; acc23[J] += h23 * w_; }
            PATHJ(0,  BF16LO(a.x))  PATHJ(1,  BF16HI(a.x))
            PATHJ(2,  BF16LO(a.y))  PATHJ(3,  BF16HI(a.y))
            PATHJ(4,  BF16LO(a.z))  PATHJ(5,  BF16HI(a.z))
            PATHJ(6,  BF16LO(a.w))  PATHJ(7,  BF16HI(a.w))
            PATHJ(8,  BF16LO(b.x))  PATHJ(9,  BF16HI(b.x))
            PATHJ(10, BF16LO(b.y))  PATHJ(11, BF16HI(b.y))
            PATHJ(12, BF16LO(b.z))  PATHJ(13, BF16HI(b.z))
            PATHJ(14, BF16LO(b.w))  PATHJ(15, BF16HI(b.w))
            PATHJ(16, BF16LO(c2.x)) PATHJ(17, BF16HI(c2.x))
            PATHJ(18, BF16LO(c2.y))
#undef PATHJ
        }
    }
    __syncthreads();   // sD ready for expansion

    // ---- Phase 4: expansion. LO=0/1 via wave slab + NT flush; LO=2 direct --
    const int w = tid >> 6;            // wave id 0..3
    const int lane = tid & 63;
    const int u = tid >> 4;            // 0..15
    const int uw = u & 3;              // u within wave
    const int v = tid & 15;
    float* slabW = &sSlab[w][0];
    int zf0 = sZero[0], zf1 = sZero[1], zf2 = sZero[2], zf3 = sZero[3];

#pragma unroll
    for (int zz = 0; zz < NPB; zz++) {
        float* gbase = out + (size_t)(zbase + zz) * (NROW * NROW);
        bool zero = (zz == 0 ? zf0 : zz == 1 ? zf1 : zz == 2 ? zf2 : zf3) != 0;
        const float* D = sD[zz];
        float A[19];
#pragma unroll
        for (int j = 0; j < 19; j++)
            A[j] = (zz == 0) ? acc01[j].x : (zz == 1) ? acc01[j].y
                 : (zz == 2) ? acc23[j].x : acc23[j].y;

        // ---- LO=0 band: rows u (4 rows/wave), slab row = uw ----
        //            NO NI  CI  PB  NUM
        expand_small<1, 1,   0,  0,  48>(A, D, slabW + uw * NROW + 0 + v * 1, zero);
        expand_small<1, 3,   1,  4,  48>(A, D, slabW + uw * NROW + 16 + v * 3, zero);
        expand_small<1, 5,   2,  8,  48>(A, D, slabW + uw * NROW + 64 + v * 5, zero);
        asm volatile("" ::: "memory");
        flush_band<4>(slabW, gbase + (4 * w) * NROW, lane);
        asm volatile("" ::: "memory");

        // ---- LO=1 band: rows 16+u*3+io (12 rows/wave), slab row = uw*3+io --
        expand_small<3, 1,   3, 16, 112>(A, D, slabW + uw * 3 * NROW + 0 + v * 1, zero);
        //          NO NI NLF CI  PB PST NUM
        expand_big <3, 3, 3,  4, 20, 12, 112>(A, D, slabW + uw * 3 * NROW + 16 + v * 3, zero);
        expand_big <3, 5, 3,  7, 56, 16, 112>(A, D, slabW + uw * 3 * NROW + 64 + v * 5, zero);
        asm volatile("" ::: "memory");
        flush_band<12>(slabW, gbase + (16 + 12 * w) * NROW, lane);
        asm volatile("" ::: "memory");

        // ---- LO=2 band: rows 64+u*5+io, direct scattered stores ----
        float* g2 = gbase + (64 + u * 5) * NROW;
        expand_small<5, 1,  10, 104,     144>(A, D, g2 + 0 + v * 1, zero);
        expand_big <5, 3, 3, 11, 112, 12, 144>(A, D, g2 + 16 + v * 3, zero);
        expand_big <5, 5, 5, 14, 172, 28, 144>(A, D, g2 + 64 + v * 5, zero);
    }
}

// ---------------------------------------------------------------------------
extern "C" void kernel_launch(void* const* d_in, const int* in_sizes, int n_in,
                              void* d_out, int out_size, void* d_ws, size_t ws_size,
                              hipStream_t stream) {
    const float* r  = (const float*)d_in[0];
    const float* W1 = (const float*)d_in[1];
    const float* b1 = (const float*)d_in[2];
    const float* W2 = (const float*)d_in[3];
    float* out = (float*)d_out;

    // 19 CG blocks + 1900 W2-repack blocks
    setup_kernel<<<19 + (NHID * 256 * 19 + 255) / 256, 256, 0, stream>>>(W2);

    const int nblocks = NB / NPB;  // 2048
    tfn_kernel<<<nblocks, 256, 0, stream>>>(r, W1, b1, out);
}

// Round 10
// 761.275 us; speedup vs baseline: 1.0538x; 1.0538x over previous
//
#include <hip/hip_runtime.h>

// ---------------------------------------------------------------------------
// Problem constants (from the reference)
//   RS_IN = RS_OUT = [(16,0),(16,1),(16,2)], HIDDEN=100
//   N_IN = N_OUT = 144, N_PATH = 4864, B = 8192, SH l=0..4 (25 comps)
// ---------------------------------------------------------------------------
#define NB     8192
#define NPB    4          // points per block -> 2048 blocks, no tail
#define NPATH  4864
#define NHID   100
#define NROW   144
#define NYSH   25
#define NDPAD  312        // padded D floats per point (io-rows padded to x4)

typedef float v4f __attribute__((ext_vector_type(4)));   // NT-store compatible
typedef float v2f __attribute__((ext_vector_type(2)));   // v_pk_fma_f32 pairs

// Repacked bf16 W2: [i][t][24 shorts]; slots 0..18 = the 19 paths thread t
// consumes in the expansion, padded to 48 B for aligned vector loads.
__device__ __align__(16) unsigned short g_w2r[NHID * 256 * 24];
__device__ float g_cg[1225];

// ---------------------------------------------------------------------------
// Setup kernel: blocks 0..18 compute CG tables (fp64, exact port of the
// reference _cg_complex/_w3j/_Q/_real_cg); blocks 19.. repack W2 to bf16.
// ---------------------------------------------------------------------------
__device__ inline double dfact(int n) {
    const double F[13] = {1., 1., 2., 6., 24., 120., 720., 5040., 40320.,
                          362880., 3628800., 39916800., 479001600.};
    return F[n];
}

__device__ double cgc(int j1, int j2, int j3, int m1, int m2, int m3) {
    if (m1 + m2 != m3) return 0.0;
    double pref0 = sqrt((2 * j3 + 1) * dfact(j1 + j2 - j3) * dfact(j1 - j2 + j3) *
                        dfact(-j1 + j2 + j3) / dfact(j1 + j2 + j3 + 1));
    double pref = pref0 * sqrt(dfact(j3 + m3) * dfact(j3 - m3) * dfact(j1 - m1) *
                               dfact(j1 + m1) * dfact(j2 - m2) * dfact(j2 + m2));
    int klo = max(0, max(j2 - j3 - m1, j1 + m2 - j3));
    int khi = min(j1 + j2 - j3, min(j1 - m1, j2 + m2));
    double s = 0.0;
    for (int k = klo; k <= khi; k++) {
        double d = dfact(k) * dfact(j1 + j2 - j3 - k) * dfact(j1 - m1 - k) *
                   dfact(j2 + m2 - k) * dfact(j3 - j2 + m1 + k) * dfact(j3 - j1 - m2 + k);
        s += ((k & 1) ? -1.0 : 1.0) / d;
    }
    return pref * s;
}

__device__ double w3jf(int j1, int j2, int j3, int m1, int m2, int m3) {
    int e = j1 - j2 + m3;
    double sgn = (e & 1) ? -1.0 : 1.0;
    return sgn / sqrt((double)(2 * j3 + 1)) * cgc(j1, j2, j3, m1, m2, -m3);
}

// Nonzeros of row `a` of the complex->real change-of-basis Q(l).
__device__ int qrow(int l, int a, int* col, double* re, double* im) {
    const double s2 = 0.70710678118654752440;
    int m = a - l;
    if (m == 0) { col[0] = l; re[0] = 1.0; im[0] = 0.0; return 1; }
    if (m > 0) {
        col[0] = l + m; re[0] = (m & 1) ? -s2 : s2; im[0] = 0.0;
        col[1] = l - m; re[1] = s2;                 im[1] = 0.0;
        return 2;
    }
    int mm = -m;
    col[0] = l - mm; re[0] = 0.0; im[0] = s2;
    col[1] = l + mm; re[1] = 0.0; im[1] = (mm & 1) ? s2 : -s2;
    return 2;
}

__global__ void setup_kernel(const float* __restrict__ W2) {
    const int tid = threadIdx.x;
    const int bid = blockIdx.x;
    if (bid >= 19) {
        // Repack W2 to bf16 (round-to-nearest-even) in [i][t][j] layout.
        // Thread t's 19 expansion paths: j -> CBJ[j] + t*NLFJ[j] + KJ[j]
        int idx = (bid - 19) * 256 + tid;
        if (idx < NHID * 256 * 19) {
            const int CBJ[19]  = {0, 256, 512, 768, 1024, 1024, 1024, 1792, 1792, 1792,
                                  2560, 2816, 2816, 2816, 3584, 3584, 3584, 3584, 3584};
            const int NLFJ[19] = {1, 1, 1, 1, 3, 3, 3, 3, 3, 3, 1, 3, 3, 3, 5, 5, 5, 5, 5};
            const int KJ[19]   = {0, 0, 0, 0, 0, 1, 2, 0, 1, 2, 0, 0, 1, 2, 0, 1, 2, 3, 4};
            int j = idx % 19;
            int t = (idx / 19) & 255;
            int i = idx / (19 * 256);
            int p = CBJ[j] + t * NLFJ[j] + KJ[j];
            unsigned int u = __float_as_uint(W2[i * NPATH + p]);
            unsigned int rr = (u + 0x7fffu + ((u >> 16) & 1u)) >> 16;
            g_w2r[(i * 256 + t) * 24 + j] = (unsigned short)rr;
        }
        return;
    }
    // CG table metadata: (lo, li, lf) in reference dict-insertion order
    const int TLO[19]  = {0,0,0,1,1,1,1,1,1,1,2,2,2,2,2,2,2,2,2};
    const int TLI[19]  = {0,1,2,0,1,1,1,2,2,2,0,1,1,1,2,2,2,2,2};
    const int TLF[19]  = {0,1,2,1,0,1,2,1,2,3,2,1,2,3,0,1,2,3,4};
    const int TOFF[19] = {0,1,10,35,44,53,80,125,170,245,350,375,420,495,600,625,700,825,1000};
    const int lo = TLO[bid], li = TLI[bid], lf = TLF[bid];
    const int n1 = 2 * lo + 1, n2 = 2 * li + 1, n3 = 2 * lf + 1;
    const int E = n1 * n2 * n3;

    __shared__ double sre[256], sim[256];
    __shared__ double snorm;
    __shared__ int ssel;

    double vre = 0.0, vim = 0.0;
    if (tid < E) {
        int g = tid % n3; int ab = tid / n3; int b = ab % n2; int a = ab / n2;
        int ca[2], cb[2], cc[2];
        double ra[2], ia[2], rb[2], ib[2], rc[2], ic[2];
        int na = qrow(lo, a, ca, ra, ia);
        int nb = qrow(li, b, cb, rb, ib);
        int nc = qrow(lf, g, cc, rc, ic);
        for (int p = 0; p < na; p++)
            for (int q = 0; q < nb; q++) {
                double pr = ra[p] * rb[q] - ia[p] * ib[q];
                double pi = ra[p] * ib[q] + ia[p] * rb[q];
                for (int s = 0; s < nc; s++) {
                    double w = w3jf(lo, li, lf, ca[p] - lo, cb[q] - li, cc[s] - lf);
                    if (w == 0.0) continue;
                    vre += (pr * rc[s] - pi * ic[s]) * w;
                    vim += (pr * ic[s] + pi * rc[s]) * w;
                }
            }
    }
    sre[tid] = vre * vre;
    sim[tid] = vim * vim;
    __syncthreads();
    if (tid == 0) {
        double sr = 0.0, si = 0.0;
        for (int e = 0; e < E; e++) { sr += sre[e]; si += sim[e]; }
        sr = sqrt(sr); si = sqrt(si);
        ssel = (sr >= si) ? 0 : 1;
        snorm = ssel ? si : sr;
    }
    __syncthreads();
    if (tid < E) {
        double val = ssel ? vim : vre;
        g_cg[TOFF[bid] + tid] = (float)(val / snorm);
    }
}

// ---------------------------------------------------------------------------
// Expansion helpers. D lives in a per-pair padded LDS layout (PB = float base,
// PST = padded io-row stride in floats; 16-B aligned). Output goes to the
// wave's LDS slab (`o`, row stride 144), NOT global.
// ---------------------------------------------------------------------------

// Pairs with NLF==1 and a single small chunk of NO*NI (<=5) floats at PB.
template <int NO, int NI, int CIDX, int PB, int NUM, int NA>
__device__ __forceinline__ void expand_small(const float (&A)[NA],
                                             const float* __restrict__ D,
                                             float* o, bool zero) {
    constexpr int T = NO * NI;
    const float PI4 = 12.566370614359172f;  // 4*pi
    const float n0 = sqrtf(NI * PI4 / (float)NUM);   // NI == 2*LI+1
    const float n1 = sqrtf(NI * PI4) * 0.25f;
    const float c0 = (zero ? n1 : n0) * A[CIDX];
    float rb[8];
    float4 t0 = *(const float4*)(D + PB);
    rb[0] = t0.x; rb[1] = t0.y; rb[2] = t0.z; rb[3] = t0.w;
    if constexpr (T > 4) rb[4] = D[PB + 4];
#pragma unroll
    for (int io = 0; io < NO; io++)
#pragma unroll
        for (int jo = 0; jo < NI; jo++)
            o[io * NROW + jo] = c0 * rb[io * NI + jo];
}

// Pairs with NLF>1: per-io float4 chunk reads of the padded row.
template <int NO, int NI, int NLF, int CIDX, int PB, int PST, int NUM, int NA>
__device__ __forceinline__ void expand_big(const float (&A)[NA],
                                           const float* __restrict__ D,
                                           float* o, bool zero) {
    constexpr int CH = (NI * NLF + 3) / 4;   // float4 chunks per io-row
    const float PI4 = 12.566370614359172f;
    const float n0 = sqrtf(NI * PI4 / (float)NUM);   // NI == 2*LI+1
    const float n1 = sqrtf(NI * PI4) * 0.25f;
    const float norm = zero ? n1 : n0;
    float c[NLF];
#pragma unroll
    for (int k = 0; k < NLF; k++) c[k] = norm * A[CIDX + k];
#pragma unroll
    for (int io = 0; io < NO; io++) {
        const float4* dp = (const float4*)(D + PB + io * PST);
        float rb[CH * 4];
#pragma unroll
        for (int q = 0; q < CH; q++) {
            float4 t = dp[q];
            rb[4 * q] = t.x; rb[4 * q + 1] = t.y; rb[4 * q + 2] = t.z; rb[4 * q + 3] = t.w;
        }
#pragma unroll
        for (int jo = 0; jo < NI; jo++) {
            float s = 0.0f;
#pragma unroll
            for (int k = 0; k < NLF; k++) s += rb[jo * NLF + k] * c[k];
            o[io * NROW + jo] = s;
        }
    }
}

// Coalesced non-temporal flush of a wave slab band: NROWS full 144-float rows.
template <int NROWS>
__device__ __forceinline__ void flush_band(const float* slabW, float* gdst,
                                           int lane) {
    constexpr int N4 = NROWS * NROW / 4;
    const v4f* s4 = (const v4f*)slabW;
    v4f* g4 = (v4f*)gdst;
#pragma unroll
    for (int c = 0; c < N4 / 64; c++) {
        v4f t = s4[c * 64 + lane];
        __builtin_nontemporal_store(t, &g4[c * 64 + lane]);
    }
    if constexpr (N4 % 64) {
        if (lane < (N4 % 64)) {
            v4f t = s4[(N4 / 64) * 64 + lane];
            __builtin_nontemporal_store(t, &g4[(N4 / 64) * 64 + lane]);
        }
    }
}

// ---------------------------------------------------------------------------
// Main fused kernel: 4 points per block, 256 threads, 2048 blocks (exact grid).
// Phases: SH+radius -> D(=CG*Y, padded) -> single-pass register GEMM with
// packed fp32 FMAs (v_pk_fma_f32: 2 points per instr; LDS-limited occupancy
// of 3 blocks/CU means the VGPR cap is ~170 -> pk accs + w[] fit, no spill)
// -> expansion into per-wave LDS slabs -> coalesced NT-store flush.
// ---------------------------------------------------------------------------
#define BF16LO(x) __uint_as_float((x) << 16)
#define BF16HI(x) __uint_as_float((x) & 0xffff0000u)

__global__ __launch_bounds__(256, 3) void tfn_kernel(const float* __restrict__ r,
                                                     const float* __restrict__ W1,
                                                     const float* __restrict__ b1,
                                                     float* __restrict__ out) {
    __shared__ float sY[NPB][NYSH];
    __shared__ float sD[NPB][NDPAD];       // 4 x 312 x 4B = 5 KB
    __shared__ float sSlab[4][20 * NROW];  // per-wave 20x144 band = 45 KB total
    __shared__ float sRad[NPB];
    __shared__ int   sZero[NPB];

    const int tid = threadIdx.x;
    const int zbase = blockIdx.x * NPB;   // 2048*4 == 8192: no tail guards

    // ---- Phase 1: radius + spherical harmonics (threads 0..NPB-1) ----
    if (tid < NPB) {
        int z = zbase + tid;
        float* Y = sY[tid];
        float x = r[3 * z], y = r[3 * z + 1], zc = r[3 * z + 2];
        float rad = sqrtf(x * x + y * y + zc * zc);
        sRad[tid] = rad;
        sZero[tid] = (rad == 0.0f) ? 1 : 0;
        float inv = 1.0f / fmaxf(rad, 1e-12f);
        x *= inv; y *= inv; zc *= inv;
        float x2 = x * x, y2 = y * y, z2 = zc * zc;
        Y[0] = 0.28209479177387814f;
        Y[1] = 0.4886025119029199f * y;
        Y[2] = 0.4886025119029199f * zc;
        Y[3] = 0.4886025119029199f * x;
        Y[4] = 1.0925484305920792f * x * y;
        Y[5] = 1.0925484305920792f * y * zc;
        Y[6] = 0.31539156525252005f * (3.0f * z2 - 1.0f);
        Y[7] = 1.0925484305920792f * x * zc;
        Y[8] = 0.5462742152960396f * (x2 - y2);
        Y[9]  = 0.5900435899266435f * y * (3.0f * x2 - y2);
        Y[10] = 2.890611442640554f * x * y * zc;
        Y[11] = 0.4570457994644658f * y * (5.0f * z2 - 1.0f);
        Y[12] = 0.3731763325901154f * zc * (5.0f * z2 - 3.0f);
        Y[13] = 0.4570457994644658f * x * (5.0f * z2 - 1.0f);
        Y[14] = 1.445305721320277f * (x2 - y2) * zc;
        Y[15] = 0.5900435899266435f * x * (x2 - 3.0f * y2);
        Y[16] = 2.5033429417967046f * x * y * (x2 - y2);
        Y[17] = 1.7701307697799304f * y * (3.0f * x2 - y2) * zc;
        Y[18] = 0.9461746957575601f * x * y * (7.0f * z2 - 1.0f);
        Y[19] = 0.6690465435572892f * y * zc * (7.0f * z2 - 3.0f);
        Y[20] = 0.10578554691520431f * (35.0f * z2 * z2 - 30.0f * z2 + 3.0f);
        Y[21] = 0.6690465435572892f * x * zc * (7.0f * z2 - 3.0f);
        Y[22] = 0.47308734787878004f * (x2 - y2) * (7.0f * z2 - 1.0f);
        Y[23] = 1.7701307697799304f * x * (x2 - 3.0f * y2) * zc;
        Y[24] = 0.6258357354491761f * (x2 * x2 - 6.0f * x2 * y2 + y2 * y2);
    }
    __syncthreads();

    // ---- Phase 2: D[pair-padded] = sum_m CG[.,.,m] * Y[lf^2+m] ----
    {
        // unpadded decomposition tables (pair order 00,01,02,10,11,12,20,21,22)
        const int dbase[10] = {0, 1, 4, 9, 12, 39, 84, 89, 134, 259};
        const int pnlf[9]   = {1, 1, 1, 1, 3, 3, 1, 3, 5};
        const int plf0[9]   = {0, 1, 2, 1, 0, 1, 2, 1, 0};
        const int ptab0[9]  = {0, 1, 2, 3, 4, 7, 10, 11, 14};
        const int toff[19]  = {0,1,10,35,44,53,80,125,170,245,350,375,420,495,600,625,700,825,1000};
        // padded layout tables
        const int PBt[9]  = {0, 4, 8, 16, 20, 56, 104, 112, 172};
        const int PSTt[9] = {0, 0, 0, 0, 12, 16, 0, 12, 28};   // 0 = single chunk
        const int NIt[9]  = {1, 3, 5, 1, 3, 5, 1, 3, 5};
        for (int idx = tid; idx < NPB * 259; idx += 256) {
            int zz = idx / 259, e = idx - zz * 259;
            int pp = 8;
            while (e < dbase[pp]) pp--;
            int le = e - dbase[pp];
            int nlf = pnlf[pp];
            int rr = le / nlf, k = le - rr * nlf;
            int lf = plf0[pp] + k, nf = 2 * lf + 1;
            const float* cg = &g_cg[toff[ptab0[pp] + k] + rr * nf];
            const float* Yp = &sY[zz][lf * lf];
            float s = 0.0f;
            for (int m = 0; m < nf; m++) s += cg[m] * Yp[m];
            int pa;
            if (PSTt[pp] == 0) {
                pa = PBt[pp] + le;
            } else {
                int io = rr / NIt[pp];
                int jo = rr - io * NIt[pp];
                pa = PBt[pp] + io * PSTt[pp] + jo * nlf + k;
            }
            sD[zz][pa] = s;
        }
    }

    // ---- Phase 3: register GEMM with packed fp32 FMAs, no LDS in the loop.
    //      acc01[j] = {coeff(z0,path j), coeff(z1,path j)}, acc23 likewise.
    float rad0 = sRad[0], rad1 = sRad[1], rad2 = sRad[2], rad3 = sRad[3];
    v2f acc01[19], acc23[19];
#pragma unroll
    for (int j = 0; j < 19; j++) { acc01[j] = (v2f)0.0f; acc23[j] = (v2f)0.0f; }
    {
        const unsigned int* wp = (const unsigned int*)g_w2r + tid * 12;  // 48 B/thread
        for (int i = 0; i < NHID; i++) {
            uint4 a  = *(const uint4*)(wp);
            uint4 b  = *(const uint4*)(wp + 4);
            uint2 c2 = *(const uint2*)(wp + 8);
            wp += 256 * 12;
            float w1i = W1[i], b1i = b1[i];          // uniform -> s_load
            float h0 = fmaxf(rad0 * w1i + b1i, 0.0f);
            float h1 = fmaxf(rad1 * w1i + b1i, 0.0f);
            float h2 = fmaxf(rad2 * w1i + b1i, 0.0f);
            float h3 = fmaxf(rad3 * w1i + b1i, 0.0f);
            v2f h01 = {h0, h1}, h23 = {h2, h3};
            // 19 paths, direct component access (no arrays -> no scratch risk),
            // each path = 2x v_pk_fma_f32 (4 FMAs in 2 instrs).
#define PATHJ(J, EXPR) { float w_ = (EXPR); acc01[J] += h01 * w_; acc23[J] += h23 * w_; }
            PATHJ(0,  BF16LO(a.x))  PATHJ(1,  BF16HI(a.x))
            PATHJ(2,  BF16LO(a.y))  PATHJ(3,  BF16HI(a.y))
            PATHJ(4,  BF16LO(a.z))  PATHJ(5,  BF16HI(a.z))
            PATHJ(6,  BF16LO(a.w))  PATHJ(7,  BF16HI(a.w))
            PATHJ(8,  BF16LO(b.x))  PATHJ(9,  BF16HI(b.x))
            PATHJ(10, BF16LO(b.y))  PATHJ(11, BF16HI(b.y))
            PATHJ(12, BF16LO(b.z))  PATHJ(13, BF16HI(b.z))
            PATHJ(14, BF16LO(b.w))  PATHJ(15, BF16HI(b.w))
            PATHJ(16, BF16LO(c2.x)) PATHJ(17, BF16HI(c2.x))
            PATHJ(18, BF16LO(c2.y))
#undef PATHJ
        }
    }
    __syncthreads();   // sD ready for expansion

    // ---- Phase 4: expansion into wave slab + coalesced NT flush ----
    const int w = tid >> 6;            // wave id 0..3
    const int lane = tid & 63;
    const int uw = (tid >> 4) & 3;     // u within wave
    const int v = tid & 15;
    float* slabW = &sSlab[w][0];
    int zf0 = sZero[0], zf1 = sZero[1], zf2 = sZero[2], zf3 = sZero[3];

#pragma unroll
    for (int zz = 0; zz < NPB; zz++) {
        float* gbase = out + (size_t)(zbase + zz) * (NROW * NROW);
        bool zero = (zz == 0 ? zf0 : zz == 1 ? zf1 : zz == 2 ? zf2 : zf3) != 0;
        const float* D = sD[zz];
        float A[19];
#pragma unroll
        for (int j = 0; j < 19; j++)
            A[j] = (zz == 0) ? acc01[j].x : (zz == 1) ? acc01[j].y
                 : (zz == 2) ? acc23[j].x : acc23[j].y;

        // ---- LO=0 band: rows u (4 rows/wave), slab row = uw ----
        //            NO NI  CI  PB  NUM
        expand_small<1, 1,   0,  0,  48>(A, D, slabW + uw * NROW + 0 + v * 1, zero);
        expand_small<1, 3,   1,  4,  48>(A, D, slabW + uw * NROW + 16 + v * 3, zero);
        expand_small<1, 5,   2,  8,  48>(A, D, slabW + uw * NROW + 64 + v * 5, zero);
        asm volatile("" ::: "memory");
        flush_band<4>(slabW, gbase + (4 * w) * NROW, lane);
        asm volatile("" ::: "memory");

        // ---- LO=1 band: rows 16+u*3+io (12 rows/wave), slab row = uw*3+io --
        expand_small<3, 1,   3, 16, 112>(A, D, slabW + uw * 3 * NROW + 0 + v * 1, zero);
        //          NO NI NLF CI  PB PST NUM
        expand_big <3, 3, 3,  4, 20, 12, 112>(A, D, slabW + uw * 3 * NROW + 16 + v * 3, zero);
        expand_big <3, 5, 3,  7, 56, 16, 112>(A, D, slabW + uw * 3 * NROW + 64 + v * 5, zero);
        asm volatile("" ::: "memory");
        flush_band<12>(slabW, gbase + (16 + 12 * w) * NROW, lane);
        asm volatile("" ::: "memory");

        // ---- LO=2 band: rows 64+u*5+io (20 rows/wave), slab row = uw*5+io --
        expand_small<5, 1,  10, 104, 144>(A, D, slabW + uw * 5 * NROW + 0 + v * 1, zero);
        expand_big <5, 3, 3, 11, 112, 12, 144>(A, D, slabW + uw * 5 * NROW + 16 + v * 3, zero);
        expand_big <5, 5, 5, 14, 172, 28, 144>(A, D, slabW + uw * 5 * NROW + 64 + v * 5, zero);
        asm volatile("" ::: "memory");
        flush_band<20>(slabW, gbase + (64 + 20 * w) * NROW, lane);
        asm volatile("" ::: "memory");
    }
}

// ---------------------------------------------------------------------------
extern "C" void kernel_launch(void* const* d_in, const int* in_sizes, int n_in,
                              void* d_out, int out_size, void* d_ws, size_t ws_size,
                              hipStream_t stream) {
    const float* r  = (const float*)d_in[0];
    const float* W1 = (const float*)d_in[1];
    const float* b1 = (const float*)d_in[2];
    const float* W2 = (const float*)d_in[3];
    float* out = (float*)d_out;

    // 19 CG blocks + 1900 W2-repack blocks
    setup_kernel<<<19 + (NHID * 256 * 19 + 255) / 256, 256, 0, stream>>>(W2);

    const int nblocks = NB / NPB;  // 2048
    tfn_kernel<<<nblocks, 256, 0, stream>>>(r, W1, b1, out);
}